// Round 15
// baseline (1224.412 us; speedup 1.0000x reference)
//
#include <hip/hip_runtime.h>
#include <hip/hip_cooperative_groups.h>
#include <hip/hip_fp16.h>

namespace cg = cooperative_groups;

// GCN 3-layer fused pipeline for MI355X.
// Primary path: ONE persistent cooperative kernel (prep -> bin -> bucket
// hist/scan/scatter -> 3x {MFMA gemm, pull-agg}) with grid.sync() between
// phases -- eliminates ~9 inter-dispatch gaps (~80us measured via accounting).
// Fallback path (if cooperative launch fails): the proven R14 10-kernel chain.

#define LRELU_SLOPE 0.1f
#define BN_EPS 1e-5f
#define BCAP 20480   // max edges per 1024-node bucket (mean 16384, ~32 sigma)
#define MGRID 1024   // cooperative grid: 256 CU x 4 blocks (LDS-bound)

typedef _Float16 half8 __attribute__((ext_vector_type(8)));
typedef float f32x4 __attribute__((ext_vector_type(4)));

__device__ __forceinline__ float2 u2f2(unsigned u) {
    __half2 h;
    *reinterpret_cast<unsigned*>(&h) = u;
    return __half22float2(h);
}

// ---------------- shared phase bodies (device functions) ----------------

union SmemU {
    _Float16 w[128 * 136];                                   // gemm W stage + Hl
    struct { int sd[1024]; int ss[1024]; int lcur[64]; } bin;
    struct { int h[1024]; int tsum[256]; int cur[1024]; int pofs; } buck;
};

struct MP {
    const float* x; const int* srcIdx; const int* dstIdx;
    const float *W1, *W2, *W3;
    const float *b1, *g1, *be1, *m1, *v1;
    const float *b2, *g2, *be2, *m2, *v2;
    const float *b3;
    int* bcur; int* row_ptr; float* dinv; int* ssrc; unsigned* pairs;
    __half* Hb; __half* Xb;
    _Float16 *W1t, *W2t, *W3t;
    float *sc1, *sh1, *sc2, *sh2, *sc3, *sh3;
    float* out;
    int N, E, nbuck;
};

__device__ void prep_body(const MP& p, int i) {
    if (i < 16384) {
        int k = i >> 7, c = i & 127;
        p.W1t[c * 136 + k] = (_Float16)p.W1[i];
    } else if (i < 32768) {
        int j = i - 16384;
        int k = j >> 7, c = j & 127;
        p.W2t[c * 136 + k] = (_Float16)p.W2[j];
    } else if (i < 40960) {
        int j = i - 32768;
        int k = j >> 6, c = j & 63;
        p.W3t[c * 136 + k] = (_Float16)p.W3[j];
    } else if (i < 41088) {
        int f = i - 40960;
        float s = p.g1[f] * rsqrtf(p.v1[f] + BN_EPS);
        p.sc1[f] = s;
        p.sh1[f] = (p.b1[f] - p.m1[f]) * s + p.be1[f];
    } else if (i < 41216) {
        int f = i - 41088;
        float s = p.g2[f] * rsqrtf(p.v2[f] + BN_EPS);
        p.sc2[f] = s;
        p.sh2[f] = (p.b2[f] - p.m2[f]) * s + p.be2[f];
    } else if (i < 41280) {
        int f = i - 41216;
        p.sc3[f] = 1.0f;
        p.sh3[f] = p.b3[f];
    } else if (i < 41344) {
        p.bcur[i - 41280] = (i - 41280) * BCAP;
    }
}

// gemm: H[r][c] = fp16((sum_k A[r][k]*W[k][c]) * dinv[r]), K = 128.
template <int NC, bool AF32>
__device__ void gemm_body(SmemU& su, const void* __restrict__ Ain,
                          const _Float16* __restrict__ Wt,
                          const float* __restrict__ dinv,
                          __half* __restrict__ H, int nrows, int tile) {
    constexpr int NT = NC / 16;
    constexpr int SPH = (NC == 128) ? 136 : 88;
    _Float16* smem = su.w;
    const int tid = threadIdx.x;
    const int row0 = tile * 64;

    {
        const uint4* src = reinterpret_cast<const uint4*>(Wt);
        uint4* dst = reinterpret_cast<uint4*>(smem);
        for (int i = tid; i < NC * 17; i += 256) dst[i] = src[i];
    }
    __syncthreads();

    const int w = tid >> 6;
    const int lane = tid & 63;
    const int l15 = lane & 15;
    const int kg = lane >> 4;

    int ar = row0 + w * 16 + l15;
    if (ar > nrows - 1) ar = nrows - 1;
    half8 a[4];
#pragma unroll
    for (int ks = 0; ks < 4; ++ks) {
        const int cb = ks * 32 + kg * 8;
        if constexpr (AF32) {
            const float* Xf = (const float*)Ain;
            const float4 x0 = *reinterpret_cast<const float4*>(&Xf[(size_t)ar * 128 + cb]);
            const float4 x1 = *reinterpret_cast<const float4*>(&Xf[(size_t)ar * 128 + cb + 4]);
            half8 av;
            av[0] = (_Float16)x0.x; av[1] = (_Float16)x0.y;
            av[2] = (_Float16)x0.z; av[3] = (_Float16)x0.w;
            av[4] = (_Float16)x1.x; av[5] = (_Float16)x1.y;
            av[6] = (_Float16)x1.z; av[7] = (_Float16)x1.w;
            a[ks] = av;
        } else {
            const __half* Xh = (const __half*)Ain;
            a[ks] = *reinterpret_cast<const half8*>(&Xh[(size_t)ar * 128 + cb]);
        }
    }

    f32x4 acc[NT];
#pragma unroll
    for (int nt = 0; nt < NT; ++nt) acc[nt] = {0.f, 0.f, 0.f, 0.f};
#pragma unroll
    for (int nt = 0; nt < NT; ++nt) {
        const int c = nt * 16 + l15;
#pragma unroll
        for (int ks = 0; ks < 4; ++ks) {
            const half8 b = *reinterpret_cast<const half8*>(&smem[c * 136 + ks * 32 + kg * 8]);
            acc[nt] = __builtin_amdgcn_mfma_f32_16x16x32_f16(a[ks], b, acc[nt], 0, 0, 0);
        }
    }
    __syncthreads();  // B-reads done; reuse smem as Hl

    float dv[4];
#pragma unroll
    for (int r = 0; r < 4; ++r) {
        int gr = row0 + w * 16 + kg * 4 + r;
        if (gr > nrows - 1) gr = nrows - 1;
        dv[r] = dinv[gr];
    }
    _Float16* Hl = smem;
#pragma unroll
    for (int nt = 0; nt < NT; ++nt) {
#pragma unroll
        for (int r = 0; r < 4; ++r) {
            Hl[(w * 16 + kg * 4 + r) * SPH + nt * 16 + l15] = (_Float16)(acc[nt][r] * dv[r]);
        }
    }
    __syncthreads();

    constexpr int CG = NC / 8;
    for (int i = tid; i < 64 * CG; i += 256) {
        const int row = i / CG, cg2 = i % CG;
        const int gr = row0 + row;
        if (gr < nrows) {
            *reinterpret_cast<uint4*>(&H[(size_t)gr * NC + cg2 * 8]) =
                *reinterpret_cast<const uint4*>(&Hl[row * SPH + cg2 * 8]);
        }
    }
    __syncthreads();  // protect Hl before any next use of smem
}

// agg: out[n][f] = act((dinv[n]*(H[n][f] + sum_e H[ssrc[e]][f]))*sc[f] + sh[f])
template <int NC, bool ACT, bool HOUT>
__device__ void agg_body(const __half* __restrict__ H, const int* __restrict__ row_ptr,
                         const int* __restrict__ ssrc, const float* __restrict__ dinv,
                         const float* __restrict__ sc, const float* __restrict__ sh,
                         void* __restrict__ out, int n, int node, int lane) {
    constexpr int FPT = NC / 32;
    const int f0 = lane * FPT;
    const int e0 = row_ptr[node];
    const int e1 = row_ptr[node + 1];

    if constexpr (FPT == 4) {
        uint2 su = *reinterpret_cast<const uint2*>(&H[(size_t)node * NC + f0]);
        float2 slo = u2f2(su.x), shi = u2f2(su.y);
        float4 A0 = {slo.x, slo.y, shi.x, shi.y};
        float4 A1 = {0, 0, 0, 0}, A2 = {0, 0, 0, 0}, A3 = {0, 0, 0, 0};
        int e = e0;
        for (; e + 7 < e1; e += 8) {
            int s[8];
#pragma unroll
            for (int j = 0; j < 8; ++j) s[j] = ssrc[e + j];
            uint2 u[8];
#pragma unroll
            for (int j = 0; j < 8; ++j)
                u[j] = *reinterpret_cast<const uint2*>(&H[(size_t)s[j] * NC + f0]);
#pragma unroll
            for (int j = 0; j < 8; ++j) {
                float2 l = u2f2(u[j].x), h = u2f2(u[j].y);
                float4& A = (j & 3) == 0 ? A0 : (j & 3) == 1 ? A1 : (j & 3) == 2 ? A2 : A3;
                A.x += l.x; A.y += l.y; A.z += h.x; A.w += h.y;
            }
        }
        for (; e < e1; ++e) {
            const uint2 u = *reinterpret_cast<const uint2*>(&H[(size_t)ssrc[e] * NC + f0]);
            float2 l = u2f2(u.x), h = u2f2(u.y);
            A1.x += l.x; A1.y += l.y; A1.z += h.x; A1.w += h.y;
        }
        float4 acc;
        acc.x = (A0.x + A1.x) + (A2.x + A3.x);
        acc.y = (A0.y + A1.y) + (A2.y + A3.y);
        acc.z = (A0.z + A1.z) + (A2.z + A3.z);
        acc.w = (A0.w + A1.w) + (A2.w + A3.w);
        const float dn = dinv[node];
        const float4 scv = *reinterpret_cast<const float4*>(&sc[f0]);
        const float4 shv = *reinterpret_cast<const float4*>(&sh[f0]);
        float o[4];
        o[0] = fmaf(acc.x * dn, scv.x, shv.x);
        o[1] = fmaf(acc.y * dn, scv.y, shv.y);
        o[2] = fmaf(acc.z * dn, scv.z, shv.z);
        o[3] = fmaf(acc.w * dn, scv.w, shv.w);
        if constexpr (ACT) {
#pragma unroll
            for (int j = 0; j < 4; ++j) o[j] = o[j] > 0.f ? o[j] : LRELU_SLOPE * o[j];
        }
        if constexpr (HOUT) {
            __half2 p0 = __floats2half2_rn(o[0], o[1]);
            __half2 p1 = __floats2half2_rn(o[2], o[3]);
            uint2 st;
            st.x = *reinterpret_cast<unsigned*>(&p0);
            st.y = *reinterpret_cast<unsigned*>(&p1);
            *reinterpret_cast<uint2*>(&((__half*)out)[(size_t)node * NC + f0]) = st;
        } else {
            float4 ov = {o[0], o[1], o[2], o[3]};
            *reinterpret_cast<float4*>(&((float*)out)[(size_t)node * NC + f0]) = ov;
        }
    } else {
        unsigned su = *reinterpret_cast<const unsigned*>(&H[(size_t)node * NC + f0]);
        float2 A0 = u2f2(su);
        float2 A1 = {0, 0}, A2 = {0, 0}, A3 = {0, 0};
        int e = e0;
        for (; e + 7 < e1; e += 8) {
            int s[8];
#pragma unroll
            for (int j = 0; j < 8; ++j) s[j] = ssrc[e + j];
            unsigned u[8];
#pragma unroll
            for (int j = 0; j < 8; ++j)
                u[j] = *reinterpret_cast<const unsigned*>(&H[(size_t)s[j] * NC + f0]);
#pragma unroll
            for (int j = 0; j < 8; ++j) {
                float2 f = u2f2(u[j]);
                float2& A = (j & 3) == 0 ? A0 : (j & 3) == 1 ? A1 : (j & 3) == 2 ? A2 : A3;
                A.x += f.x; A.y += f.y;
            }
        }
        for (; e < e1; ++e) {
            float2 f = u2f2(*reinterpret_cast<const unsigned*>(&H[(size_t)ssrc[e] * NC + f0]));
            A1.x += f.x; A1.y += f.y;
        }
        float2 acc;
        acc.x = (A0.x + A1.x) + (A2.x + A3.x);
        acc.y = (A0.y + A1.y) + (A2.y + A3.y);
        const float dn = dinv[node];
        const float2 scv = *reinterpret_cast<const float2*>(&sc[f0]);
        const float2 shv = *reinterpret_cast<const float2*>(&sh[f0]);
        float o0 = fmaf(acc.x * dn, scv.x, shv.x);
        float o1 = fmaf(acc.y * dn, scv.y, shv.y);
        if constexpr (ACT) {
            o0 = o0 > 0.f ? o0 : LRELU_SLOPE * o0;
            o1 = o1 > 0.f ? o1 : LRELU_SLOPE * o1;
        }
        if constexpr (HOUT) {
            __half2 p0 = __floats2half2_rn(o0, o1);
            *reinterpret_cast<unsigned*>(&((__half*)out)[(size_t)node * NC + f0]) =
                *reinterpret_cast<unsigned*>(&p0);
        } else {
            float2 ov = {o0, o1};
            *reinterpret_cast<float2*>(&((float*)out)[(size_t)node * NC + f0]) = ov;
        }
    }
}

template <int NC, bool AF32>
__device__ void gemm_phase(SmemU& su, const void* Ain, const _Float16* Wt,
                           const float* dinv, __half* H, int nrows) {
    const int gb = (nrows + 63) / 64;
    for (int tile = blockIdx.x; tile < gb; tile += gridDim.x)
        gemm_body<NC, AF32>(su, Ain, Wt, dinv, H, nrows, tile);
}

template <int NC, bool ACT, bool HOUT>
__device__ void agg_phase(const __half* H, const int* row_ptr, const int* ssrc,
                          const float* dinv, const float* sc, const float* sh,
                          void* out, int n) {
    const int tid = threadIdx.x;
    const int lane = tid & 31;
    const int ng = (n + 7) >> 3;
    for (int g = blockIdx.x; g < ng; g += gridDim.x) {
        const int node = g * 8 + (tid >> 5);
        if (node < n)
            agg_body<NC, ACT, HOUT>(H, row_ptr, ssrc, dinv, sc, sh, out, n, node, lane);
    }
}

// ---------------- cooperative mega-kernel ----------------

__global__ __launch_bounds__(256, 4) void mega(MP p) {
    __shared__ SmemU su;
    cg::grid_group grid = cg::this_grid();
    const int tid = threadIdx.x;
    const int gsz = gridDim.x;

    // P0: prep (W transposes, sc/sh fold, bcur init)
    for (int i = blockIdx.x * 256 + tid; i < 41344; i += gsz * 256)
        prep_body(p, i);
    grid.sync();

    // P1: bin edges into per-bucket packed (src<<10 | dst&1023) uint32
    {
        const int chunk = (p.E + gsz - 1) / gsz;  // 782 at E=800k, G=1024
        const int e0 = blockIdx.x * chunk;
        const int ecnt = min(chunk, p.E - e0);    // block-uniform
        if (ecnt > 0) {
            int* sd = su.bin.sd;
            int* ss = su.bin.ss;
            int* lcur = su.bin.lcur;
            for (int j = tid; j < ecnt; j += 256) {
                sd[j] = p.dstIdx[e0 + j];
                ss[j] = p.srcIdx[e0 + j];
            }
            if (tid < 64) lcur[tid] = 0;
            __syncthreads();
            for (int j = tid; j < ecnt; j += 256) atomicAdd(&lcur[sd[j] >> 10], 1);
            __syncthreads();
            if (tid < 64) lcur[tid] = atomicAdd(&p.bcur[tid], lcur[tid]);
            __syncthreads();
            for (int j = tid; j < ecnt; j += 256) {
                const int d = sd[j];
                const int pos = atomicAdd(&lcur[d >> 10], 1);
                p.pairs[pos] = ((unsigned)ss[j] << 10) | (unsigned)(d & 1023);
            }
        }
    }
    grid.sync();

    // P2: per-bucket hist + scan + row_ptr/dinv + local scatter
    for (int b = blockIdx.x; b < p.nbuck; b += gsz) {
        const int base = b << 10;
        const int nn = min(1024, p.N - base);
        const int cntb = p.bcur[b] - b * BCAP;
        int* h = su.buck.h;
        int* tsum = su.buck.tsum;
        int* cur = su.buck.cur;
        for (int i = tid; i < 1024; i += 256) h[i] = 0;
        __syncthreads();
        const unsigned* pb = p.pairs + (size_t)b * BCAP;
        for (int j = tid; j < cntb; j += 256) atomicAdd(&h[pb[j] & 1023u], 1);
        __syncthreads();
        const int i4 = tid * 4;
        const int a0 = h[i4], a1 = h[i4 + 1], a2 = h[i4 + 2], a3 = h[i4 + 3];
        const int s1 = a0 + a1, s2 = s1 + a2, tot = s2 + a3;
        tsum[tid] = tot;
        __syncthreads();
        for (int off = 1; off < 256; off <<= 1) {
            int t = (tid >= off) ? tsum[tid - off] : 0;
            __syncthreads();
            tsum[tid] += t;
            __syncthreads();
        }
        if (tid == 0) {  // bucket totals come straight from bcur
            int acc = 0;
            for (int i = 0; i < b; ++i) acc += p.bcur[i] - i * BCAP;
            su.buck.pofs = acc;
        }
        __syncthreads();
        const int g0 = su.buck.pofs + tsum[tid] - tot;
        const int rp[4] = {g0, g0 + a0, g0 + s1, g0 + s2};
        const int av[4] = {a0, a1, a2, a3};
#pragma unroll
        for (int q = 0; q < 4; ++q) {
            const int node = i4 + q;
            cur[node] = rp[q];
            if (node < nn) {
                p.row_ptr[base + node] = rp[q];
                p.dinv[base + node] = rsqrtf(1.0f + (float)av[q]);
            }
        }
        __syncthreads();
        for (int j = tid; j < cntb; j += 256) {
            const unsigned pr = pb[j];
            const int pos = atomicAdd(&cur[pr & 1023u], 1);
            p.ssrc[pos] = (int)(pr >> 10);
        }
        __syncthreads();
    }
    if (blockIdx.x == 0 && tid == 0) p.row_ptr[p.N] = p.E;
    grid.sync();

    // Layers
    gemm_phase<128, true>(su, p.x, p.W1t, p.dinv, p.Hb, p.N);
    grid.sync();
    agg_phase<128, true, true>(p.Hb, p.row_ptr, p.ssrc, p.dinv, p.sc1, p.sh1, p.Xb, p.N);
    grid.sync();
    gemm_phase<128, false>(su, p.Xb, p.W2t, p.dinv, p.Hb, p.N);
    grid.sync();
    agg_phase<128, true, true>(p.Hb, p.row_ptr, p.ssrc, p.dinv, p.sc2, p.sh2, p.Xb, p.N);
    grid.sync();
    gemm_phase<64, false>(su, p.Xb, p.W3t, p.dinv, p.Hb, p.N);
    grid.sync();
    agg_phase<64, false, false>(p.Hb, p.row_ptr, p.ssrc, p.dinv, p.sc3, p.sh3, p.out, p.N);
}

// ---------------- fallback kernels (R14 path, proven @261.8us) ----------------

__global__ void prep_all_k(MP p) {
    int i = blockIdx.x * 256 + threadIdx.x;
    if (i < 41344) prep_body(p, i);
}

__global__ __launch_bounds__(256) void bin_pass_k(MP p) {
    __shared__ int sd[1664], ss[1664];
    __shared__ int lcur[64];
    const int tid = threadIdx.x;
    const int chunk = (p.E + gridDim.x - 1) / gridDim.x;
    const int e0 = blockIdx.x * chunk;
    const int ecnt = min(chunk, p.E - e0);
    for (int j = tid; j < ecnt; j += 256) {
        sd[j] = p.dstIdx[e0 + j];
        ss[j] = p.srcIdx[e0 + j];
    }
    if (tid < 64) lcur[tid] = 0;
    __syncthreads();
    for (int j = tid; j < ecnt; j += 256) atomicAdd(&lcur[sd[j] >> 10], 1);
    __syncthreads();
    if (tid < 64) lcur[tid] = atomicAdd(&p.bcur[tid], lcur[tid]);
    __syncthreads();
    for (int j = tid; j < ecnt; j += 256) {
        const int d = sd[j];
        const int pos = atomicAdd(&lcur[d >> 10], 1);
        p.pairs[pos] = ((unsigned)ss[j] << 10) | (unsigned)(d & 1023);
    }
}

__global__ __launch_bounds__(1024) void hist_scan_k(MP p, int* __restrict__ part) {
    __shared__ int h[1024];
    __shared__ int s[1024];
    const int b = blockIdx.x;
    const int tid = threadIdx.x;
    const int base = b << 10;
    const int nn = min(1024, p.N - base);
    const int cntb = p.bcur[b] - b * BCAP;
    h[tid] = 0;
    __syncthreads();
    const unsigned* pb = p.pairs + (size_t)b * BCAP;
    for (int j = tid; j < cntb; j += 1024) atomicAdd(&h[pb[j] & 1023u], 1);
    __syncthreads();
    const int v = h[tid];
    s[tid] = v;
    __syncthreads();
    for (int off = 1; off < 1024; off <<= 1) {
        int t = (tid >= off) ? s[tid - off] : 0;
        __syncthreads();
        s[tid] += t;
        __syncthreads();
    }
    if (tid < nn) {
        p.row_ptr[base + tid] = s[tid] - v;
        p.dinv[base + tid] = rsqrtf(1.0f + (float)v);
    }
    if (tid == 1023) part[b] = s[1023];
}

__global__ __launch_bounds__(1024) void csr_scatter_k(MP p, const int* __restrict__ part) {
    __shared__ int cur[1024];
    __shared__ int pofs;
    const int b = blockIdx.x;
    const int tid = threadIdx.x;
    const int base = b << 10;
    const int nn = min(1024, p.N - base);
    const int cntb = p.bcur[b] - b * BCAP;
    if (tid < 64) {
        int v = (tid < b) ? part[tid] : 0;
#pragma unroll
        for (int off = 32; off; off >>= 1) v += __shfl_down(v, off, 64);
        if (tid == 0) pofs = v;
    }
    __syncthreads();
    const int pof = pofs;
    if (tid < nn) {
        const int rp = p.row_ptr[base + tid] + pof;
        p.row_ptr[base + tid] = rp;
        cur[tid] = rp;
    }
    if (b == p.nbuck - 1 && tid == 0) p.row_ptr[p.N] = p.E;
    __syncthreads();
    const unsigned* pb = p.pairs + (size_t)b * BCAP;
    for (int j = tid; j < cntb; j += 1024) {
        const unsigned pr = pb[j];
        const int pos = atomicAdd(&cur[pr & 1023u], 1);
        p.ssrc[pos] = (int)(pr >> 10);
    }
}

template <int NC, bool AF32>
__global__ __launch_bounds__(256) void gemm_k(const void* __restrict__ Ain,
                                              const _Float16* __restrict__ Wt,
                                              const float* __restrict__ dinv,
                                              __half* __restrict__ H, int nrows) {
    __shared__ SmemU su;
    gemm_body<NC, AF32>(su, Ain, Wt, dinv, H, nrows, blockIdx.x);
}

template <int NC, bool ACT, bool HOUT>
__global__ __launch_bounds__(256) void agg_k(const __half* __restrict__ H,
                                             const int* __restrict__ row_ptr,
                                             const int* __restrict__ ssrc,
                                             const float* __restrict__ dinv,
                                             const float* __restrict__ sc,
                                             const float* __restrict__ sh,
                                             void* __restrict__ out, int n) {
    const int tid = threadIdx.x;
    const int node = blockIdx.x * 8 + (tid >> 5);
    if (node < n)
        agg_body<NC, ACT, HOUT>(H, row_ptr, ssrc, dinv, sc, sh, out, n, node, tid & 31);
}

// ---------------- launcher ----------------

extern "C" void kernel_launch(void* const* d_in, const int* in_sizes, int n_in,
                              void* d_out, int out_size, void* d_ws, size_t ws_size,
                              hipStream_t stream) {
    MP p;
    p.x   = (const float*)d_in[0];
    const int* ei = (const int*)d_in[1];
    p.W1  = (const float*)d_in[2];
    p.b1  = (const float*)d_in[3];
    p.g1  = (const float*)d_in[4];
    p.be1 = (const float*)d_in[5];
    p.m1  = (const float*)d_in[6];
    p.v1  = (const float*)d_in[7];
    p.W2  = (const float*)d_in[8];
    p.b2  = (const float*)d_in[9];
    p.g2  = (const float*)d_in[10];
    p.be2 = (const float*)d_in[11];
    p.m2  = (const float*)d_in[12];
    p.v2  = (const float*)d_in[13];
    p.W3  = (const float*)d_in[14];
    p.b3  = (const float*)d_in[15];
    p.out = (float*)d_out;

    p.N = in_sizes[0] / 128;
    p.E = in_sizes[1] / 2;
    p.srcIdx = ei;
    p.dstIdx = ei + p.E;
    p.nbuck = (p.N + 1023) >> 10;

    char* ptr = (char*)d_ws;
    auto carve = [&](size_t bytes) -> void* {
        void* r = (void*)ptr;
        ptr += (bytes + 255) & ~(size_t)255;
        return r;
    };
    int* part  = (int*)carve(1024);
    p.row_ptr  = (int*)carve((size_t)(p.N + 1) * 4);
    p.bcur     = (int*)carve(64 * 4);
    p.dinv     = (float*)carve((size_t)p.N * 4);
    p.ssrc     = (int*)carve((size_t)p.E * 4);
    p.pairs    = (unsigned*)carve((size_t)p.nbuck * BCAP * 4);
    p.Hb       = (__half*)carve((size_t)p.N * 128 * 2);
    p.Xb       = (__half*)carve((size_t)p.N * 128 * 2);
    p.W1t      = (_Float16*)carve(128 * 136 * 2);
    p.W2t      = (_Float16*)carve(128 * 136 * 2);
    p.W3t      = (_Float16*)carve(64 * 136 * 2);
    p.sc1      = (float*)carve(128 * 4);
    p.sh1      = (float*)carve(128 * 4);
    p.sc2      = (float*)carve(128 * 4);
    p.sh2      = (float*)carve(128 * 4);
    p.sc3      = (float*)carve(64 * 4);
    p.sh3      = (float*)carve(64 * 4);
    (void)ws_size; (void)n_in; (void)out_size;

    // Primary: single cooperative kernel (needs MGRID co-resident blocks).
    void* kargs[] = {&p};
    hipError_t err = hipLaunchCooperativeKernel(
        reinterpret_cast<void*>(&mega), dim3(MGRID), dim3(256), kargs, 0, stream);
    if (err == hipSuccess) return;
    (void)hipGetLastError();  // clear sticky error; fall back

    // Fallback: proven 10-kernel chain (R14, 261.8us).
    const int gb = (p.N + 63) / 64;
    const int ab = (p.N + 7) / 8;
    prep_all_k<<<162, 256, 0, stream>>>(p);
    bin_pass_k<<<512, 256, 0, stream>>>(p);
    hist_scan_k<<<p.nbuck, 1024, 0, stream>>>(p, part);
    csr_scatter_k<<<p.nbuck, 1024, 0, stream>>>(p, part);
    gemm_k<128, true><<<gb, 256, 0, stream>>>(p.x, p.W1t, p.dinv, p.Hb, p.N);
    agg_k<128, true, true><<<ab, 256, 0, stream>>>(p.Hb, p.row_ptr, p.ssrc, p.dinv, p.sc1, p.sh1, p.Xb, p.N);
    gemm_k<128, false><<<gb, 256, 0, stream>>>(p.Xb, p.W2t, p.dinv, p.Hb, p.N);
    agg_k<128, true, true><<<ab, 256, 0, stream>>>(p.Hb, p.row_ptr, p.ssrc, p.dinv, p.sc2, p.sh2, p.Xb, p.N);
    gemm_k<64, false><<<gb, 256, 0, stream>>>(p.Xb, p.W3t, p.dinv, p.Hb, p.N);
    agg_k<64, false, false><<<ab, 256, 0, stream>>>(p.Hb, p.row_ptr, p.ssrc, p.dinv, p.sc3, p.sh3, p.out, p.N);
}